// Round 1
// baseline (2227.828 us; speedup 1.0000x reference)
//
#include <hip/hip_runtime.h>
#include <math.h>

#define NLVL 8
#define TSIZE 1024
#define PR1 2654435761u
#define PR2 805459861u

struct Res8 { float r[NLVL]; };

__global__ __launch_bounds__(256, 2)
void ngp_fused_kernel(const float* __restrict__ x,
                      const float* __restrict__ table,
                      const float* __restrict__ w1,
                      const float* __restrict__ w2,
                      const float* __restrict__ r1,
                      const float* __restrict__ r2,
                      const float* __restrict__ r3,
                      float* __restrict__ out,
                      int N, int iters, Res8 res)
{
    // 8 levels x 1024 entries x 2 features = 64 KB. LDS-resident table:
    // random 8B gathers broadcast/conflict in LDS far better than thrashing 32KB L1.
    __shared__ float2 tab[NLVL * TSIZE];

    {   // cooperative load: 16384 floats = 4096 float4, 16 per thread, coalesced
        const float4* src = (const float4*)table;
        float4* dst = (float4*)tab;
        #pragma unroll
        for (int k = 0; k < 16; ++k)
            dst[threadIdx.x + 256 * k] = src[threadIdx.x + 256 * k];
    }
    __syncthreads();

    const int stride = gridDim.x * blockDim.x;
    const int gid = blockIdx.x * blockDim.x + threadIdx.x;

    for (int it = 0; it < iters; ++it) {        // uniform trip count -> weight loads stay scalar (SMEM)
        int i = gid + it * stride;
        int ic = i < N ? i : N - 1;             // clamp instead of branching around the body

        float px = x[3*ic+0] + 0.5f;
        float py = x[3*ic+1] + 0.5f;
        float pz = x[3*ic+2] + 0.5f;

        // ---- hash-grid encode: 8 levels, trilinear over 8 corners ----
        float h[16];
        #pragma unroll
        for (int l = 0; l < NLVL; ++l) {
            const float rf = res.r[l];
            float fx = px * rf, fy = py * rf, fz = pz * rf;
            float bx = floorf(fx), by = floorf(fy), bz = floorf(fz);
            float wx = fx - bx, wy = fy - by, wz = fz - bz;
            unsigned ix = (unsigned)bx, iy = (unsigned)by, iz = (unsigned)bz;
            unsigned hx0 = ix,        hx1 = ix + 1u;
            unsigned hy0 = iy * PR1,  hy1 = hy0 + PR1;   // (iy+1)*PR1 mod 2^32
            unsigned hz0 = iz * PR2,  hz1 = hz0 + PR2;
            float wx0 = 1.0f - wx, wy0 = 1.0f - wy, wz0 = 1.0f - wz;
            float wyz00 = wy0*wz0, wyz01 = wy0*wz, wyz10 = wy*wz0, wyz11 = wy*wz;
            const float2* tl = tab + (l << 10);
            float f0 = 0.0f, f1 = 0.0f;
            #define CRN(HX,HY,HZ,W) { unsigned e = ((HX)^(HY)^(HZ)) & (TSIZE-1u); \
                                      float2 t = tl[e]; float wg = (W); \
                                      f0 = fmaf(wg, t.x, f0); f1 = fmaf(wg, t.y, f1); }
            CRN(hx0, hy0, hz0, wx0*wyz00)
            CRN(hx0, hy0, hz1, wx0*wyz01)
            CRN(hx0, hy1, hz0, wx0*wyz10)
            CRN(hx0, hy1, hz1, wx0*wyz11)
            CRN(hx1, hy0, hz0, wx *wyz00)
            CRN(hx1, hy0, hz1, wx *wyz01)
            CRN(hx1, hy1, hz0, wx *wyz10)
            CRN(hx1, hy1, hz1, wx *wyz11)
            #undef CRN
            h[2*l+0] = f0; h[2*l+1] = f1;
        }

        // ---- MLP: 16 ->(w1) 64 relu ->(w2) 16 ->(r1) 64 relu ->(r2) 64 relu ->(r3) 1 sigmoid
        // Weight reads are wave-uniform constant offsets -> compiler emits s_load (K$),
        // so the VALU sees a pure FMA stream. All loops fully unrolled: register arrays
        // must have compile-time indices or they spill to scratch.
        float a[64];
        #pragma unroll
        for (int j = 0; j < 64; ++j) a[j] = 0.0f;
        #pragma unroll
        for (int ii = 0; ii < 16; ++ii) {
            float hv = h[ii];
            #pragma unroll
            for (int j = 0; j < 64; ++j)
                a[j] = fmaf(hv, w1[ii*64 + j], a[j]);
        }
        #pragma unroll
        for (int j = 0; j < 64; ++j) a[j] = fmaxf(a[j], 0.0f);

        float h2[16];
        #pragma unroll
        for (int j = 0; j < 16; ++j) h2[j] = 0.0f;
        #pragma unroll
        for (int k = 0; k < 64; ++k) {
            float av = a[k];
            #pragma unroll
            for (int j = 0; j < 16; ++j)
                h2[j] = fmaf(av, w2[k*16 + j], h2[j]);
        }

        float g[64];
        #pragma unroll
        for (int j = 0; j < 64; ++j) g[j] = 0.0f;
        #pragma unroll
        for (int ii = 0; ii < 16; ++ii) {
            float hv = h2[ii];
            #pragma unroll
            for (int j = 0; j < 64; ++j)
                g[j] = fmaf(hv, r1[ii*64 + j], g[j]);
        }
        #pragma unroll
        for (int j = 0; j < 64; ++j) g[j] = fmaxf(g[j], 0.0f);

        // r2 (64x64) + relu + r3 (64x1), chunked 4x16 to cap live registers at g[64]+s[16]
        float z = 0.0f;
        #pragma unroll
        for (int jb = 0; jb < 4; ++jb) {
            float s[16];
            #pragma unroll
            for (int j = 0; j < 16; ++j) s[j] = 0.0f;
            #pragma unroll
            for (int k = 0; k < 64; ++k) {
                float gv = g[k];
                #pragma unroll
                for (int j = 0; j < 16; ++j)
                    s[j] = fmaf(gv, r2[k*64 + jb*16 + j], s[j]);
            }
            #pragma unroll
            for (int j = 0; j < 16; ++j)
                z = fmaf(fmaxf(s[j], 0.0f), r3[jb*16 + j], z);
        }

        if (i < N)
            out[i] = 1.0f / (1.0f + __expf(-z));
    }
}

extern "C" void kernel_launch(void* const* d_in, const int* in_sizes, int n_in,
                              void* d_out, int out_size, void* d_ws, size_t ws_size,
                              hipStream_t stream)
{
    const float* x  = (const float*)d_in[0];
    const float* tb = (const float*)d_in[1];
    const float* w1 = (const float*)d_in[2];
    const float* w2 = (const float*)d_in[3];
    const float* r1 = (const float*)d_in[4];
    const float* r2 = (const float*)d_in[5];
    const float* r3 = (const float*)d_in[6];
    float* out = (float*)d_out;
    const int N = in_sizes[0] / 3;

    // Replicate numpy: B_SCALE = exp(log(20*0.5/2)/(L-1)); RES = floor(2 * B_SCALE**l)
    // (glibc doubles, same libm the harness host uses)
    Res8 res;
    double b = exp(log(20.0 * 0.5 / 2.0) / (double)(NLVL - 1));
    for (int l = 0; l < NLVL; ++l)
        res.r[l] = (float)floor(2.0 * pow(b, (double)l));

    const int blocks = 1024, threads = 256;
    const int iters = (N + blocks * threads - 1) / (blocks * threads);
    ngp_fused_kernel<<<blocks, threads, 0, stream>>>(x, tb, w1, w2, r1, r2, r3,
                                                     out, N, iters, res);
}

// Round 2
// 195.715 us; speedup vs baseline: 11.3830x; 11.3830x over previous
//
#include <hip/hip_runtime.h>
#include <math.h>

#define NLVL 8
#define PR1 2654435761u
#define PR2 805459861u

typedef _Float16 half8 __attribute__((ext_vector_type(8)));
typedef float floatx4 __attribute__((ext_vector_type(4)));

struct Res8 { float r[NLVL]; };

__device__ __forceinline__ unsigned packh2(float a, float b) {
    union { _Float16 h[2]; unsigned u; } p;
    p.h[0] = (_Float16)a; p.h[1] = (_Float16)b;
    return p.u;
}
__device__ __forceinline__ half8 as_h8(uint4 u) {
    union { uint4 u; half8 h; } c; c.u = u; return c.h;
}

// Fused NGP: hash-grid encode (f16 table in LDS) + 5-layer MLP on MFMA.
// All layers computed transposed (Y^T = W^T @ X^T) so MFMA C/D frags hold 4
// CONSECUTIVE features of one point -> 1 packed b64 LDS write per 16-col chunk,
// and B frags are 1 b128 read. Per-wave staging => no __syncthreads in the loop.
__global__ __launch_bounds__(256, 3)
void ngp_mfma_kernel(const float* __restrict__ x,
                     const float* __restrict__ table,
                     const float* __restrict__ w1,
                     const float* __restrict__ w2,
                     const float* __restrict__ r1,
                     const float* __restrict__ r2,
                     const float* __restrict__ r3,
                     float* __restrict__ out,
                     int N, int iters, Res8 res)
{
    __shared__ unsigned tab[NLVL * 1024];   // 32 KB: (f0,f1) packed as 2 x f16
    __shared__ unsigned hstg[4][512];       // 8 KB: per-wave h staging, 64 pts x 8 dwords
    __shared__ unsigned astg[4][512];       // 8 KB: per-wave act staging, 16 pts x 32 dwords

    const int tid  = threadIdx.x;
    const int lane = tid & 63, wv = tid >> 6;
    const int m16  = lane & 15, q = lane >> 4;
    const int swz  = (m16 & 7) << 2;        // XOR swizzle (4-dword blocks) breaks stride-128B conflicts

    // ---- stage table: global f32 pairs -> packed f16 dwords (coalesced) ----
    {
        const float2* src = (const float2*)table;
        #pragma unroll
        for (int k = 0; k < 32; ++k) {
            int i = tid + 256 * k;
            float2 v = src[i];
            tab[i] = packh2(v.x, v.y);
        }
    }

    // ---- preload weight A-frags (W^T), f16, held in VGPRs for the whole kernel ----
    // A[m][k]: m = lane&15 (out-feature within 16-chunk), k = (lane>>4)*8 + j (in-feature)
    half8 A1[4], A2[2], A3[4], A4[2][4];
    #pragma unroll
    for (int mo = 0; mo < 4; ++mo)
        #pragma unroll
        for (int j = 0; j < 8; ++j) {
            int k = q * 8 + j;                               // K padded 16->32: upper half zero
            A1[mo][j] = (k < 16) ? (_Float16)w1[k * 64 + mo * 16 + m16] : (_Float16)0.f;
            A3[mo][j] = (k < 16) ? (_Float16)r1[k * 64 + mo * 16 + m16] : (_Float16)0.f;
        }
    #pragma unroll
    for (int kc = 0; kc < 2; ++kc)
        #pragma unroll
        for (int j = 0; j < 8; ++j) {
            int k = kc * 32 + q * 8 + j;
            A2[kc][j] = (_Float16)w2[k * 16 + m16];
            #pragma unroll
            for (int mo = 0; mo < 4; ++mo)
                A4[kc][mo][j] = (_Float16)r2[k * 64 + mo * 16 + m16];
        }
    float r3v[16];
    #pragma unroll
    for (int mo = 0; mo < 4; ++mo)
        #pragma unroll
        for (int r = 0; r < 4; ++r)
            r3v[mo * 4 + r] = r3[mo * 16 + q * 4 + r];

    __syncthreads();                         // table visible to all waves; only barrier in the kernel

    unsigned* hs = hstg[wv];
    unsigned* as = astg[wv];
    const floatx4 cz = {0.f, 0.f, 0.f, 0.f};

    #pragma unroll 1
    for (int it = 0; it < iters; ++it) {
        const int pbase = (it * (int)gridDim.x + (int)blockIdx.x) * 256;
        int p  = pbase + tid;
        int ic = p < N ? p : N - 1;

        float px = x[3 * ic + 0] + 0.5f;
        float py = x[3 * ic + 1] + 0.5f;
        float pz = x[3 * ic + 2] + 0.5f;

        // ---- encode: one point per lane, 8 levels, trilinear over 8 hashed corners ----
        unsigned hd[8];
        #pragma unroll
        for (int l = 0; l < NLVL; ++l) {
            const float rf = res.r[l];
            float fx = px * rf, fy = py * rf, fz = pz * rf;
            float bx = floorf(fx), by = floorf(fy), bz = floorf(fz);
            float wx = fx - bx, wy = fy - by, wz = fz - bz;
            unsigned ix = (unsigned)bx, iy = (unsigned)by, iz = (unsigned)bz;
            unsigned hx0 = ix,       hx1 = ix + 1u;
            unsigned hy0 = iy * PR1, hy1 = hy0 + PR1;
            unsigned hz0 = iz * PR2, hz1 = hz0 + PR2;
            float wx0 = 1.0f - wx, wy0 = 1.0f - wy, wz0 = 1.0f - wz;
            float wyz00 = wy0 * wz0, wyz01 = wy0 * wz, wyz10 = wy * wz0, wyz11 = wy * wz;
            const unsigned* tl = tab + (l << 10);
            float f0 = 0.f, f1 = 0.f;
            #define CRN(HX,HY,HZ,W) { unsigned e = ((HX)^(HY)^(HZ)) & 1023u;          \
                                      union { unsigned u; _Float16 h[2]; } cv;        \
                                      cv.u = tl[e]; float wg = (W);                   \
                                      f0 = fmaf(wg, (float)cv.h[0], f0);              \
                                      f1 = fmaf(wg, (float)cv.h[1], f1); }
            CRN(hx0, hy0, hz0, wx0 * wyz00)
            CRN(hx0, hy0, hz1, wx0 * wyz01)
            CRN(hx0, hy1, hz0, wx0 * wyz10)
            CRN(hx0, hy1, hz1, wx0 * wyz11)
            CRN(hx1, hy0, hz0, wx  * wyz00)
            CRN(hx1, hy0, hz1, wx  * wyz01)
            CRN(hx1, hy1, hz0, wx  * wyz10)
            CRN(hx1, hy1, hz1, wx  * wyz11)
            #undef CRN
            hd[l] = packh2(f0, f1);          // dword l = features (2l, 2l+1)
        }
        *(uint4*)&hs[lane * 8]     = make_uint4(hd[0], hd[1], hd[2], hd[3]);
        *(uint4*)&hs[lane * 8 + 4] = make_uint4(hd[4], hd[5], hd[6], hd[7]);

        // ---- MLP: 4 tiles of 16 points, all intra-wave ----
        #pragma unroll
        for (int t = 0; t < 4; ++t) {
            // L1: act1^T = relu(W1^T @ h^T)   (K=16 padded to 32)
            uint4 bu = *(const uint4*)&hs[(t * 16 + m16) * 8 + (q & 1) * 4];
            if (q >= 2) { bu.x = 0u; bu.y = 0u; bu.z = 0u; bu.w = 0u; }
            half8 b1 = as_h8(bu);
            #pragma unroll
            for (int mo = 0; mo < 4; ++mo) {
                floatx4 c = __builtin_amdgcn_mfma_f32_16x16x32_f16(A1[mo], b1, cz, 0, 0, 0);
                unsigned lo = packh2(fmaxf(c[0], 0.f), fmaxf(c[1], 0.f));
                unsigned hi = packh2(fmaxf(c[2], 0.f), fmaxf(c[3], 0.f));
                int dw = mo * 8 + q * 2;
                *(uint2*)&as[m16 * 32 + (dw ^ swz)] = make_uint2(lo, hi);
            }
            // L2: h2^T = W2^T @ act1^T   (linear, K=64)
            uint4 u0 = *(const uint4*)&as[m16 * 32 + ((q * 4) ^ swz)];
            uint4 u1 = *(const uint4*)&as[m16 * 32 + ((16 + q * 4) ^ swz)];
            floatx4 c2 = __builtin_amdgcn_mfma_f32_16x16x32_f16(A2[0], as_h8(u0), cz, 0, 0, 0);
            c2 = __builtin_amdgcn_mfma_f32_16x16x32_f16(A2[1], as_h8(u1), c2, 0, 0, 0);
            {
                unsigned lo = packh2(c2[0], c2[1]);
                unsigned hi = packh2(c2[2], c2[3]);
                int dw = q * 2;
                *(uint2*)&as[m16 * 32 + (dw ^ swz)] = make_uint2(lo, hi);
            }
            // L3: act2^T = relu(R1^T @ h2^T)   (K=16 padded to 32)
            uint4 b3u = *(const uint4*)&as[m16 * 32 + (((q & 1) * 4) ^ swz)];
            if (q >= 2) { b3u.x = 0u; b3u.y = 0u; b3u.z = 0u; b3u.w = 0u; }
            half8 b3 = as_h8(b3u);
            #pragma unroll
            for (int mo = 0; mo < 4; ++mo) {
                floatx4 c = __builtin_amdgcn_mfma_f32_16x16x32_f16(A3[mo], b3, cz, 0, 0, 0);
                unsigned lo = packh2(fmaxf(c[0], 0.f), fmaxf(c[1], 0.f));
                unsigned hi = packh2(fmaxf(c[2], 0.f), fmaxf(c[3], 0.f));
                int dw = mo * 8 + q * 2;
                *(uint2*)&as[m16 * 32 + (dw ^ swz)] = make_uint2(lo, hi);
            }
            // L4: g = relu(R2^T @ act2^T); L5: z = g . r3 on VALU + 2 shuffles
            uint4 g0 = *(const uint4*)&as[m16 * 32 + ((q * 4) ^ swz)];
            uint4 g1 = *(const uint4*)&as[m16 * 32 + ((16 + q * 4) ^ swz)];
            half8 b40 = as_h8(g0), b41 = as_h8(g1);
            float z = 0.f;
            #pragma unroll
            for (int mo = 0; mo < 4; ++mo) {
                floatx4 c = __builtin_amdgcn_mfma_f32_16x16x32_f16(A4[0][mo], b40, cz, 0, 0, 0);
                c = __builtin_amdgcn_mfma_f32_16x16x32_f16(A4[1][mo], b41, c, 0, 0, 0);
                #pragma unroll
                for (int r = 0; r < 4; ++r)
                    z = fmaf(fmaxf(c[r], 0.f), r3v[mo * 4 + r], z);
            }
            z += __shfl_xor(z, 16);
            z += __shfl_xor(z, 32);
            if (lane < 16) {
                int op = pbase + wv * 64 + t * 16 + lane;
                if (op < N) out[op] = 1.0f / (1.0f + __expf(-z));
            }
        }
    }
}

extern "C" void kernel_launch(void* const* d_in, const int* in_sizes, int n_in,
                              void* d_out, int out_size, void* d_ws, size_t ws_size,
                              hipStream_t stream)
{
    const float* x  = (const float*)d_in[0];
    const float* tb = (const float*)d_in[1];
    const float* w1 = (const float*)d_in[2];
    const float* w2 = (const float*)d_in[3];
    const float* r1 = (const float*)d_in[4];
    const float* r2 = (const float*)d_in[5];
    const float* r3 = (const float*)d_in[6];
    float* out = (float*)d_out;
    const int N = in_sizes[0] / 3;

    // Replicate numpy: B_SCALE = exp(log(20*0.5/2)/(L-1)); RES = floor(2 * B_SCALE**l)
    Res8 res;
    double b = exp(log(20.0 * 0.5 / 2.0) / (double)(NLVL - 1));
    for (int l = 0; l < NLVL; ++l)
        res.r[l] = (float)floor(2.0 * pow(b, (double)l));

    const int blocks = 512, threads = 256;           // 2 blk/CU-worth of waves; LDS allows 3/CU
    const int per = blocks * threads;
    const int iters = (N + per - 1) / per;           // 16 for N = 2M
    ngp_mfma_kernel<<<blocks, threads, 0, stream>>>(x, tb, w1, w2, r1, r2, r3,
                                                    out, N, iters, res);
}

// Round 4
// 171.030 us; speedup vs baseline: 13.0259x; 1.1443x over previous
//
#include <hip/hip_runtime.h>
#include <math.h>

#define NLVL 8
#define PR1 2654435761u
#define PR2 805459861u

typedef __fp16    h2v   __attribute__((ext_vector_type(2)));   // matches cvt_pkrtz return type
typedef _Float16  half8 __attribute__((ext_vector_type(8)));   // MFMA operand type
typedef float     floatx4 __attribute__((ext_vector_type(4)));

union UH2 { unsigned u; h2v h; };

struct Res8 { float r[NLVL]; };

__device__ __forceinline__ unsigned pk2(float a, float b) {
    UH2 c; c.h = __builtin_amdgcn_cvt_pkrtz(a, b); return c.u;   // 1 instr: f32x2 -> packed f16x2
}
__device__ __forceinline__ half8 as_h8(uint4 u) {
    union { uint4 u; half8 h; } c; c.u = u; return c.h;
}
__device__ __forceinline__ h2v lerp2(h2v a, h2v b, h2v t) {
    return a + t * (b - a);                                      // v_pk_add/sub/fma_f16
}

// Fused NGP: hash-grid encode (packed-f16 table in LDS, lerp-tree trilinear on
// v_pk_*_f16) + 5-layer MLP on MFMA, all transposed (Y^T = W^T X^T) so C/D
// frags pack straight into b64 LDS writes. Per-wave staging => no barrier in
// the main loop. 48 KB LDS -> 3 blocks/CU.
__global__ __launch_bounds__(256, 3)
void ngp_mfma_kernel(const float* __restrict__ x,
                     const float* __restrict__ table,
                     const float* __restrict__ w1,
                     const float* __restrict__ w2,
                     const float* __restrict__ r1,
                     const float* __restrict__ r2,
                     const float* __restrict__ r3,
                     float* __restrict__ out,
                     int N, int iters, Res8 res)
{
    __shared__ unsigned tab[NLVL * 1024];   // 32 KB: (f0,f1) packed f16x2 per entry
    __shared__ unsigned hstg[4][512];       // 8 KB: per-wave h staging
    __shared__ unsigned astg[4][512];       // 8 KB: per-wave activation staging

    const int tid  = threadIdx.x;
    const int lane = tid & 63, wv = tid >> 6;
    const int m16  = lane & 15, q = lane >> 4;
    const int swz  = (m16 & 7) << 2;        // XOR swizzle breaks stride-128B conflicts

    {   // stage table: f32 pairs -> packed f16 dwords (coalesced, one-time)
        const float2* src = (const float2*)table;
        #pragma unroll
        for (int k = 0; k < 32; ++k) {
            int i = tid + 256 * k;
            float2 v = src[i];
            tab[i] = pk2(v.x, v.y);
        }
    }

    // preload weight A-frags (W^T) into VGPRs for the whole kernel.
    // A[m][k]: m = lane&15 (out-feature in 16-chunk), k = (lane>>4)*8 + j
    half8 A1[4], A2[2], A3[4], A4[2][4];
    #pragma unroll
    for (int mo = 0; mo < 4; ++mo)
        #pragma unroll
        for (int j = 0; j < 8; ++j) {
            int k = q * 8 + j;                               // K padded 16->32
            A1[mo][j] = (k < 16) ? (_Float16)w1[k * 64 + mo * 16 + m16] : (_Float16)0.f;
            A3[mo][j] = (k < 16) ? (_Float16)r1[k * 64 + mo * 16 + m16] : (_Float16)0.f;
        }
    #pragma unroll
    for (int kc = 0; kc < 2; ++kc)
        #pragma unroll
        for (int j = 0; j < 8; ++j) {
            int k = kc * 32 + q * 8 + j;
            A2[kc][j] = (_Float16)w2[k * 16 + m16];
            #pragma unroll
            for (int mo = 0; mo < 4; ++mo)
                A4[kc][mo][j] = (_Float16)r2[k * 64 + mo * 16 + m16];
        }
    float r3v[16];
    #pragma unroll
    for (int mo = 0; mo < 4; ++mo)
        #pragma unroll
        for (int r = 0; r < 4; ++r)
            r3v[mo * 4 + r] = r3[mo * 16 + q * 4 + r];

    __syncthreads();                        // only barrier in the kernel

    unsigned* hs = hstg[wv];
    unsigned* as = astg[wv];
    const floatx4 cz = {0.f, 0.f, 0.f, 0.f};

    #pragma unroll 1
    for (int it = 0; it < iters; ++it) {
        const int pbase = (it * (int)gridDim.x + (int)blockIdx.x) * 256;
        int p  = pbase + tid;
        int ic = p < N ? p : N - 1;          // clamp; store is guarded below

        float px = x[3 * ic + 0] + 0.5f;
        float py = x[3 * ic + 1] + 0.5f;
        float pz = x[3 * ic + 2] + 0.5f;

        // ---- encode: 8 levels, trilinear as a 7-lerp tree on packed f16 ----
        unsigned hd[8];
        #pragma unroll
        for (int l = 0; l < NLVL; ++l) {
            const float rf = res.r[l];
            float fx = px * rf, fy = py * rf, fz = pz * rf;
            float bx = floorf(fx), by = floorf(fy), bz = floorf(fz);
            UH2 wxp, wyp, wzp;
            wxp.h = __builtin_amdgcn_cvt_pkrtz(fx - bx, fx - bx);
            wyp.h = __builtin_amdgcn_cvt_pkrtz(fy - by, fy - by);
            wzp.h = __builtin_amdgcn_cvt_pkrtz(fz - bz, fz - bz);
            unsigned ix = (unsigned)bx, iy = (unsigned)by, iz = (unsigned)bz;
            unsigned y0f = iy * PR1, z0f = iz * PR2;
            // mask distributes over XOR: pre-mask all six axis hashes
            unsigned x0 = ix & 1023u,         x1 = (ix + 1u) & 1023u;
            unsigned y0 = y0f & 1023u,        y1 = (y0f + PR1) & 1023u;
            unsigned z0 = z0f & 1023u,        z1 = (z0f + PR2) & 1023u;
            unsigned a00 = x0 ^ y0, a01 = x0 ^ y1, a10 = x1 ^ y0, a11 = x1 ^ y1;
            const unsigned* tl = tab + (l << 10);
            UH2 c000, c001, c010, c011, c100, c101, c110, c111;
            c000.u = tl[a00 ^ z0]; c001.u = tl[a00 ^ z1];
            c010.u = tl[a01 ^ z0]; c011.u = tl[a01 ^ z1];
            c100.u = tl[a10 ^ z0]; c101.u = tl[a10 ^ z1];
            c110.u = tl[a11 ^ z0]; c111.u = tl[a11 ^ z1];
            h2v zz00 = lerp2(c000.h, c001.h, wzp.h);
            h2v zz01 = lerp2(c010.h, c011.h, wzp.h);
            h2v zz10 = lerp2(c100.h, c101.h, wzp.h);
            h2v zz11 = lerp2(c110.h, c111.h, wzp.h);
            h2v yy0  = lerp2(zz00, zz01, wyp.h);
            h2v yy1  = lerp2(zz10, zz11, wyp.h);
            UH2 r; r.h = lerp2(yy0, yy1, wxp.h);
            hd[l] = r.u;                     // already packed: features (2l, 2l+1)
        }
        *(uint4*)&hs[lane * 8]     = make_uint4(hd[0], hd[1], hd[2], hd[3]);
        *(uint4*)&hs[lane * 8 + 4] = make_uint4(hd[4], hd[5], hd[6], hd[7]);

        // ---- MLP: 4 tiles of 16 points, all intra-wave ----
        #pragma unroll
        for (int t = 0; t < 4; ++t) {
            // L1: act1^T = relu(W1^T @ h^T)   (K=16 padded to 32)
            uint4 bu = *(const uint4*)&hs[(t * 16 + m16) * 8 + (q & 1) * 4];
            if (q >= 2) { bu.x = 0u; bu.y = 0u; bu.z = 0u; bu.w = 0u; }
            half8 b1 = as_h8(bu);
            #pragma unroll
            for (int mo = 0; mo < 4; ++mo) {
                floatx4 c = __builtin_amdgcn_mfma_f32_16x16x32_f16(A1[mo], b1, cz, 0, 0, 0);
                unsigned lo = pk2(fmaxf(c[0], 0.f), fmaxf(c[1], 0.f));
                unsigned hi = pk2(fmaxf(c[2], 0.f), fmaxf(c[3], 0.f));
                int dw = mo * 8 + q * 2;
                *(uint2*)&as[m16 * 32 + (dw ^ swz)] = make_uint2(lo, hi);
            }
            // L2: h2^T = W2^T @ act1^T   (linear, K=64)
            uint4 u0 = *(const uint4*)&as[m16 * 32 + ((q * 4) ^ swz)];
            uint4 u1 = *(const uint4*)&as[m16 * 32 + ((16 + q * 4) ^ swz)];
            floatx4 c2 = __builtin_amdgcn_mfma_f32_16x16x32_f16(A2[0], as_h8(u0), cz, 0, 0, 0);
            c2 = __builtin_amdgcn_mfma_f32_16x16x32_f16(A2[1], as_h8(u1), c2, 0, 0, 0);
            {
                int dw = q * 2;
                *(uint2*)&as[m16 * 32 + (dw ^ swz)] =
                    make_uint2(pk2(c2[0], c2[1]), pk2(c2[2], c2[3]));
            }
            // L3: act2^T = relu(R1^T @ h2^T)   (K=16 padded to 32)
            uint4 b3u = *(const uint4*)&as[m16 * 32 + (((q & 1) * 4) ^ swz)];
            if (q >= 2) { b3u.x = 0u; b3u.y = 0u; b3u.z = 0u; b3u.w = 0u; }
            half8 b3 = as_h8(b3u);
            #pragma unroll
            for (int mo = 0; mo < 4; ++mo) {
                floatx4 c = __builtin_amdgcn_mfma_f32_16x16x32_f16(A3[mo], b3, cz, 0, 0, 0);
                unsigned lo = pk2(fmaxf(c[0], 0.f), fmaxf(c[1], 0.f));
                unsigned hi = pk2(fmaxf(c[2], 0.f), fmaxf(c[3], 0.f));
                int dw = mo * 8 + q * 2;
                *(uint2*)&as[m16 * 32 + (dw ^ swz)] = make_uint2(lo, hi);
            }
            // L4: g = relu(R2^T @ act2^T); L5: z = g . r3 on VALU + 2 shuffles
            uint4 g0 = *(const uint4*)&as[m16 * 32 + ((q * 4) ^ swz)];
            uint4 g1 = *(const uint4*)&as[m16 * 32 + ((16 + q * 4) ^ swz)];
            half8 b40 = as_h8(g0), b41 = as_h8(g1);
            float z = 0.f;
            #pragma unroll
            for (int mo = 0; mo < 4; ++mo) {
                floatx4 c = __builtin_amdgcn_mfma_f32_16x16x32_f16(A4[0][mo], b40, cz, 0, 0, 0);
                c = __builtin_amdgcn_mfma_f32_16x16x32_f16(A4[1][mo], b41, c, 0, 0, 0);
                #pragma unroll
                for (int r = 0; r < 4; ++r)
                    z = fmaf(fmaxf(c[r], 0.f), r3v[mo * 4 + r], z);
            }
            z += __shfl_xor(z, 16);
            z += __shfl_xor(z, 32);
            if (lane < 16) {
                int op = pbase + wv * 64 + t * 16 + lane;
                if (op < N) out[op] = 1.0f / (1.0f + __expf(-z));
            }
        }
    }
}

extern "C" void kernel_launch(void* const* d_in, const int* in_sizes, int n_in,
                              void* d_out, int out_size, void* d_ws, size_t ws_size,
                              hipStream_t stream)
{
    const float* x  = (const float*)d_in[0];
    const float* tb = (const float*)d_in[1];
    const float* w1 = (const float*)d_in[2];
    const float* w2 = (const float*)d_in[3];
    const float* r1 = (const float*)d_in[4];
    const float* r2 = (const float*)d_in[5];
    const float* r3 = (const float*)d_in[6];
    float* out = (float*)d_out;
    const int N = in_sizes[0] / 3;

    // Replicate numpy: B_SCALE = exp(log(20*0.5/2)/(L-1)); RES = floor(2 * B_SCALE**l)
    Res8 res;
    double b = exp(log(20.0 * 0.5 / 2.0) / (double)(NLVL - 1));
    for (int l = 0; l < NLVL; ++l)
        res.r[l] = (float)floor(2.0 * pow(b, (double)l));

    // 768 blocks = 3 blocks/CU resident (LDS 48KB x 3 = 144KB <= 160KB),
    // uniform iteration count everywhere (tail clamped).
    const int blocks = 768, threads = 256;
    const int per = blocks * threads;
    const int iters = (N + per - 1) / per;
    ngp_mfma_kernel<<<blocks, threads, 0, stream>>>(x, tb, w1, w2, r1, r2, r3,
                                                    out, N, iters, res);
}

// Round 5
// 149.745 us; speedup vs baseline: 14.8775x; 1.1421x over previous
//
#include <hip/hip_runtime.h>
#include <math.h>

#define NLVL 8
#define PR1 2654435761u
#define PR2 805459861u

typedef __fp16    h2v   __attribute__((ext_vector_type(2)));   // matches cvt_pkrtz return type
typedef _Float16  half8 __attribute__((ext_vector_type(8)));   // MFMA operand type
typedef float     floatx4 __attribute__((ext_vector_type(4)));

union UH2 { unsigned u; h2v h; };

struct Res8 { float r[NLVL]; };

__device__ __forceinline__ unsigned pk2(float a, float b) {
    UH2 c; c.h = __builtin_amdgcn_cvt_pkrtz(a, b); return c.u;   // 1 instr
}
__device__ __forceinline__ unsigned pkrelu(float a, float b) {   // pack, then v_pk_max_f16
    UH2 c; c.h = __builtin_amdgcn_cvt_pkrtz(a, b);
    h2v z = {(__fp16)0.f, (__fp16)0.f};
    c.h = __builtin_elementwise_max(c.h, z);
    return c.u;
}
__device__ __forceinline__ half8 as_h8(uint4 u) {
    union { uint4 u; half8 h; } c; c.u = u; return c.h;
}
__device__ __forceinline__ h2v lerp2(h2v a, h2v b, h2v t) {
    return a + t * (b - a);                                      // v_pk_sub + v_pk_fma
}

// Fused NGP: hash-grid encode (packed-f16 table in LDS, lerp-tree trilinear) +
// 5-layer MLP on MFMA, all transposed (Y^T = W^T X^T). Per-wave staging => no
// barrier in the main loop. 512-thr blocks share one 32KB table across 8 waves:
// 64KB/block -> 2 blocks/CU -> 16 waves/CU (vs 12 at 256-thr).
__global__ __launch_bounds__(512, 4)
void ngp_mfma_kernel(const float* __restrict__ x,
                     const float* __restrict__ table,
                     const float* __restrict__ w1,
                     const float* __restrict__ w2,
                     const float* __restrict__ r1,
                     const float* __restrict__ r2,
                     const float* __restrict__ r3,
                     float* __restrict__ out,
                     int N, int iters, Res8 res)
{
    __shared__ unsigned tab[NLVL * 1024];   // 32 KB packed f16x2
    __shared__ unsigned hstg[8][512];       // 16 KB: per-wave h staging
    __shared__ unsigned astg[8][512];       // 16 KB: per-wave act staging

    const int tid  = threadIdx.x;
    const int lane = tid & 63, wv = tid >> 6;
    const int m16  = lane & 15, q = lane >> 4;
    const int swz  = (m16 & 7) << 2;        // XOR swizzle breaks stride-128B conflicts

    {   // stage table: f32 pairs -> packed f16 dwords (coalesced, one-time)
        const float2* src = (const float2*)table;
        #pragma unroll
        for (int k = 0; k < 32; ++k) {
            int i = tid + 512 * k;
            float2 v = src[i];
            tab[i] = pk2(v.x, v.y);
        }
    }

    // preload weight A-frags (W^T) into VGPRs for the whole kernel.
    // A[m][k]: m = lane&15 (out-feature in 16-chunk), k = (lane>>4)*8 + j
    half8 A1[4], A2[2], A3[4], A4[2][4];
    #pragma unroll
    for (int mo = 0; mo < 4; ++mo)
        #pragma unroll
        for (int j = 0; j < 8; ++j) {
            int k = q * 8 + j;                               // K padded 16->32
            A1[mo][j] = (k < 16) ? (_Float16)w1[k * 64 + mo * 16 + m16] : (_Float16)0.f;
            A3[mo][j] = (k < 16) ? (_Float16)r1[k * 64 + mo * 16 + m16] : (_Float16)0.f;
        }
    #pragma unroll
    for (int kc = 0; kc < 2; ++kc)
        #pragma unroll
        for (int j = 0; j < 8; ++j) {
            int k = kc * 32 + q * 8 + j;
            A2[kc][j] = (_Float16)w2[k * 16 + m16];
            #pragma unroll
            for (int mo = 0; mo < 4; ++mo)
                A4[kc][mo][j] = (_Float16)r2[k * 64 + mo * 16 + m16];
        }
    float r3v[16];
    #pragma unroll
    for (int mo = 0; mo < 4; ++mo)
        #pragma unroll
        for (int r = 0; r < 4; ++r)
            r3v[mo * 4 + r] = r3[mo * 16 + q * 4 + r];

    __syncthreads();                        // only barrier in the kernel

    unsigned* hs = hstg[wv];
    unsigned* as = astg[wv];
    const char* tabb = (const char*)tab;    // byte-addressed gathers
    const floatx4 cz = {0.f, 0.f, 0.f, 0.f};

    #pragma unroll 1
    for (int it = 0; it < iters; ++it) {
        const int pbase = (it * (int)gridDim.x + (int)blockIdx.x) * 512;
        int p  = pbase + tid;
        int ic = p < N ? p : N - 1;          // clamp; store is guarded below

        float px = x[3 * ic + 0] + 0.5f;
        float py = x[3 * ic + 1] + 0.5f;
        float pz = x[3 * ic + 2] + 0.5f;

        // ---- encode: 8 levels, trilinear as a 7-lerp tree on packed f16.
        // Axis hashes pre-shifted to BYTE offsets (mask 4092 distributes over
        // XOR and commutes with +PR since (a&1023)<<2 == (a<<2)&4092):
        // per-corner address = one XOR, level base folds into ds imm offset.
        unsigned hd[8];
        #pragma unroll
        for (int l = 0; l < NLVL; ++l) {
            const float rf = res.r[l];
            float fx = px * rf, fy = py * rf, fz = pz * rf;
            float bx = floorf(fx), by = floorf(fy), bz = floorf(fz);
            UH2 wxp, wyp, wzp;
            wxp.h = __builtin_amdgcn_cvt_pkrtz(fx - bx, fx - bx);
            wyp.h = __builtin_amdgcn_cvt_pkrtz(fy - by, fy - by);
            wzp.h = __builtin_amdgcn_cvt_pkrtz(fz - bz, fz - bz);
            unsigned ix = (unsigned)bx, iy = (unsigned)by, iz = (unsigned)bz;
            unsigned x0 = (ix << 2) & 4092u,          x1 = (x0 + 4u) & 4092u;
            unsigned y0 = ((iy * PR1) << 2) & 4092u,  y1 = (y0 + (PR1 << 2)) & 4092u;
            unsigned z0 = ((iz * PR2) << 2) & 4092u,  z1 = (z0 + (PR2 << 2)) & 4092u;
            unsigned a00 = x0 ^ y0, a01 = x0 ^ y1, a10 = x1 ^ y0, a11 = x1 ^ y1;
            const char* tlb = tabb + (l << 12);
            UH2 c000, c001, c010, c011, c100, c101, c110, c111;
            c000.u = *(const unsigned*)(tlb + (a00 ^ z0));
            c001.u = *(const unsigned*)(tlb + (a00 ^ z1));
            c010.u = *(const unsigned*)(tlb + (a01 ^ z0));
            c011.u = *(const unsigned*)(tlb + (a01 ^ z1));
            c100.u = *(const unsigned*)(tlb + (a10 ^ z0));
            c101.u = *(const unsigned*)(tlb + (a10 ^ z1));
            c110.u = *(const unsigned*)(tlb + (a11 ^ z0));
            c111.u = *(const unsigned*)(tlb + (a11 ^ z1));
            h2v zz00 = lerp2(c000.h, c001.h, wzp.h);
            h2v zz01 = lerp2(c010.h, c011.h, wzp.h);
            h2v zz10 = lerp2(c100.h, c101.h, wzp.h);
            h2v zz11 = lerp2(c110.h, c111.h, wzp.h);
            h2v yy0  = lerp2(zz00, zz01, wyp.h);
            h2v yy1  = lerp2(zz10, zz11, wyp.h);
            UH2 r; r.h = lerp2(yy0, yy1, wxp.h);
            hd[l] = r.u;                     // already packed: features (2l, 2l+1)
        }
        *(uint4*)&hs[lane * 8]     = make_uint4(hd[0], hd[1], hd[2], hd[3]);
        *(uint4*)&hs[lane * 8 + 4] = make_uint4(hd[4], hd[5], hd[6], hd[7]);

        // ---- MLP: 4 tiles of 16 points, all intra-wave ----
        // NOTE: no B zeroing for the K=16->32 padded layers: the k>=16 half of
        // A1/A3 is zero, and the dwords q>=2 lanes read are finite valid data,
        // so those lanes contribute exactly 0.
        #pragma unroll
        for (int t = 0; t < 4; ++t) {
            // L1: act1^T = relu(W1^T @ h^T)   (K=16 padded to 32)
            half8 b1 = as_h8(*(const uint4*)&hs[(t * 16 + m16) * 8 + (q & 1) * 4]);
            #pragma unroll
            for (int mo = 0; mo < 4; ++mo) {
                floatx4 c = __builtin_amdgcn_mfma_f32_16x16x32_f16(A1[mo], b1, cz, 0, 0, 0);
                int dw = mo * 8 + q * 2;
                *(uint2*)&as[m16 * 32 + (dw ^ swz)] =
                    make_uint2(pkrelu(c[0], c[1]), pkrelu(c[2], c[3]));
            }
            // L2: h2^T = W2^T @ act1^T   (linear, K=64)
            uint4 u0 = *(const uint4*)&as[m16 * 32 + ((q * 4) ^ swz)];
            uint4 u1 = *(const uint4*)&as[m16 * 32 + ((16 + q * 4) ^ swz)];
            floatx4 c2 = __builtin_amdgcn_mfma_f32_16x16x32_f16(A2[0], as_h8(u0), cz, 0, 0, 0);
            c2 = __builtin_amdgcn_mfma_f32_16x16x32_f16(A2[1], as_h8(u1), c2, 0, 0, 0);
            {
                int dw = q * 2;
                *(uint2*)&as[m16 * 32 + (dw ^ swz)] =
                    make_uint2(pk2(c2[0], c2[1]), pk2(c2[2], c2[3]));
            }
            // L3: act2^T = relu(R1^T @ h2^T)   (K=16 padded to 32)
            half8 b3 = as_h8(*(const uint4*)&as[m16 * 32 + (((q & 1) * 4) ^ swz)]);
            #pragma unroll
            for (int mo = 0; mo < 4; ++mo) {
                floatx4 c = __builtin_amdgcn_mfma_f32_16x16x32_f16(A3[mo], b3, cz, 0, 0, 0);
                int dw = mo * 8 + q * 2;
                *(uint2*)&as[m16 * 32 + (dw ^ swz)] =
                    make_uint2(pkrelu(c[0], c[1]), pkrelu(c[2], c[3]));
            }
            // L4: g = relu(R2^T @ act2^T); L5: z = g . r3 on VALU + 2 shuffles
            uint4 g0 = *(const uint4*)&as[m16 * 32 + ((q * 4) ^ swz)];
            uint4 g1 = *(const uint4*)&as[m16 * 32 + ((16 + q * 4) ^ swz)];
            half8 b40 = as_h8(g0), b41 = as_h8(g1);
            float z = 0.f;
            #pragma unroll
            for (int mo = 0; mo < 4; ++mo) {
                floatx4 c = __builtin_amdgcn_mfma_f32_16x16x32_f16(A4[0][mo], b40, cz, 0, 0, 0);
                c = __builtin_amdgcn_mfma_f32_16x16x32_f16(A4[1][mo], b41, c, 0, 0, 0);
                #pragma unroll
                for (int r = 0; r < 4; ++r)
                    z = fmaf(fmaxf(c[r], 0.f), r3v[mo * 4 + r], z);
            }
            z += __shfl_xor(z, 16);
            z += __shfl_xor(z, 32);
            if (lane < 16) {
                int op = pbase + wv * 64 + t * 16 + lane;
                if (op < N) out[op] = 1.0f / (1.0f + __expf(-z));
            }
        }
    }
}

extern "C" void kernel_launch(void* const* d_in, const int* in_sizes, int n_in,
                              void* d_out, int out_size, void* d_ws, size_t ws_size,
                              hipStream_t stream)
{
    const float* x  = (const float*)d_in[0];
    const float* tb = (const float*)d_in[1];
    const float* w1 = (const float*)d_in[2];
    const float* w2 = (const float*)d_in[3];
    const float* r1 = (const float*)d_in[4];
    const float* r2 = (const float*)d_in[5];
    const float* r3 = (const float*)d_in[6];
    float* out = (float*)d_out;
    const int N = in_sizes[0] / 3;

    // Replicate numpy: B_SCALE = exp(log(20*0.5/2)/(L-1)); RES = floor(2 * B_SCALE**l)
    Res8 res;
    double b = exp(log(20.0 * 0.5 / 2.0) / (double)(NLVL - 1));
    for (int l = 0; l < NLVL; ++l)
        res.r[l] = (float)floor(2.0 * pow(b, (double)l));

    // 512 blocks x 512 threads: 64KB LDS/block -> 2 blocks/CU -> 16 waves/CU.
    // 512*512*8 == 2M exactly: no clamped-tail waste.
    const int blocks = 512, threads = 512;
    const int per = blocks * threads;
    const int iters = (N + per - 1) / per;
    ngp_mfma_kernel<<<blocks, threads, 0, stream>>>(x, tb, w1, w2, r1, r2, r3,
                                                    out, N, iters, res);
}

// Round 7
// 142.527 us; speedup vs baseline: 15.6309x; 1.0506x over previous
//
#include <hip/hip_runtime.h>
#include <math.h>

#define NLVL 8
#define PR1 2654435761u
#define PR2 805459861u

typedef __fp16    h2v   __attribute__((ext_vector_type(2)));   // cvt_pkrtz return type
typedef _Float16  half4 __attribute__((ext_vector_type(4)));   // 16x16x16 MFMA A/B operand
typedef float     floatx4 __attribute__((ext_vector_type(4)));

// NOTE: legacy K=16 MFMA builtins use the no-underscore dtype suffix on gfx950.
#define MFMA16(a,b,c) __builtin_amdgcn_mfma_f32_16x16x16f16(a,b,c,0,0,0)

union UH2 { unsigned u; h2v h; };

struct Res8 { float r[NLVL]; };

__device__ __forceinline__ unsigned pk2(float a, float b) {
    UH2 c; c.h = __builtin_amdgcn_cvt_pkrtz(a, b); return c.u;
}
__device__ __forceinline__ unsigned pkrelu(float a, float b) {
    UH2 c; c.h = __builtin_amdgcn_cvt_pkrtz(a, b);
    h2v z = {(__fp16)0.f, (__fp16)0.f};
    c.h = __builtin_elementwise_max(c.h, z);
    return c.u;
}
__device__ __forceinline__ half4 as_h4(uint2 u) {
    union { uint2 u; half4 h; } c; c.u = u; return c.h;
}
__device__ __forceinline__ h2v lerp2(h2v a, h2v b, h2v t) {
    return a + t * (b - a);
}

// Fused NGP, register-resident MLP chain:
// For mfma_f32_16x16x16f16, C/D frag (row=q*4+r, col=m16) == B frag
// (k=q*4+j, n=m16) of the next K=16 chunk. Splitting every 64-wide layer into
// four 16-row chunks lets each layer's output pack IN-REGISTER (2x cvt_pkrtz)
// into the next layer's B frags -> zero LDS between layers. Only the
// encode->L1 transpose touches LDS (stride-10 pad caps conflicts at 4-way).
__global__ __launch_bounds__(512, 4)
void ngp_mfma_kernel(const float* __restrict__ x,
                     const float* __restrict__ table,
                     const float* __restrict__ w1,
                     const float* __restrict__ w2,
                     const float* __restrict__ r1,
                     const float* __restrict__ r2,
                     const float* __restrict__ r3,
                     float* __restrict__ out,
                     int N, int iters, Res8 res)
{
    __shared__ unsigned tab[NLVL * 1024];   // 32 KB packed f16x2
    __shared__ unsigned hstg[8][640];       // 20 KB: 64 pts x 10 dw (stride-10 pad)

    const int tid  = threadIdx.x;
    const int lane = tid & 63, wv = tid >> 6;
    const int m16  = lane & 15, q = lane >> 4;

    {   // stage table: 8192 float2 -> 8192 packed dwords (16/thread @ 512 thr)
        const float2* src = (const float2*)table;
        #pragma unroll
        for (int k = 0; k < 16; ++k) {
            int i = tid + 512 * k;
            float2 v = src[i];
            tab[i] = pk2(v.x, v.y);
        }
    }

    // Preload weight A-frags (W^T) for 16x16x16: A[m=m16][k=q*4+j].
    // A1(4)+A2(4)+A3(4)+A4(16) frags x 2 VGPR = 56 VGPRs, resident all kernel.
    half4 A1[4], A2[4], A3[4], A4[4][4];
    #pragma unroll
    for (int mo = 0; mo < 4; ++mo)
        #pragma unroll
        for (int j = 0; j < 4; ++j) {
            int k = q * 4 + j;
            A1[mo][j] = (_Float16)w1[k * 64 + mo * 16 + m16];
            A3[mo][j] = (_Float16)r1[k * 64 + mo * 16 + m16];
            A2[mo][j] = (_Float16)w2[(mo * 16 + k) * 16 + m16];   // mo = K-chunk here
            #pragma unroll
            for (int kc = 0; kc < 4; ++kc)
                A4[kc][mo][j] = (_Float16)r2[(kc * 16 + k) * 64 + mo * 16 + m16];
        }
    float r3v[16];
    #pragma unroll
    for (int mo = 0; mo < 4; ++mo)
        #pragma unroll
        for (int r = 0; r < 4; ++r)
            r3v[mo * 4 + r] = r3[mo * 16 + q * 4 + r];

    __syncthreads();                        // table visible; only barrier in kernel

    unsigned* hs = hstg[wv];
    const char* tabb = (const char*)tab;
    const floatx4 cz = {0.f, 0.f, 0.f, 0.f};

    #pragma unroll 1
    for (int it = 0; it < iters; ++it) {
        const int pbase = (it * (int)gridDim.x + (int)blockIdx.x) * 512;
        int p = pbase + tid;                 // grid*threads*iters == N exactly

        float px = x[3 * p + 0] + 0.5f;
        float py = x[3 * p + 1] + 0.5f;
        float pz = x[3 * p + 2] + 0.5f;

        // ---- encode: 8 levels, 7-lerp trilinear tree on packed f16.
        // Axis hashes pre-shifted to byte offsets; per-corner addr = one XOR.
        unsigned hd[8];
        #pragma unroll
        for (int l = 0; l < NLVL; ++l) {
            const float rf = res.r[l];
            float fx = px * rf, fy = py * rf, fz = pz * rf;
            float bx = floorf(fx), by = floorf(fy), bz = floorf(fz);
            UH2 wxp, wyp, wzp;
            wxp.h = __builtin_amdgcn_cvt_pkrtz(fx - bx, fx - bx);
            wyp.h = __builtin_amdgcn_cvt_pkrtz(fy - by, fy - by);
            wzp.h = __builtin_amdgcn_cvt_pkrtz(fz - bz, fz - bz);
            unsigned ix = (unsigned)bx, iy = (unsigned)by, iz = (unsigned)bz;
            unsigned x0 = (ix << 2) & 4092u,          x1 = (x0 + 4u) & 4092u;
            unsigned y0 = ((iy * PR1) << 2) & 4092u,  y1 = (y0 + (PR1 << 2)) & 4092u;
            unsigned z0 = ((iz * PR2) << 2) & 4092u,  z1 = (z0 + (PR2 << 2)) & 4092u;
            unsigned a00 = x0 ^ y0, a01 = x0 ^ y1, a10 = x1 ^ y0, a11 = x1 ^ y1;
            const char* tlb = tabb + (l << 12);
            UH2 c000, c001, c010, c011, c100, c101, c110, c111;
            c000.u = *(const unsigned*)(tlb + (a00 ^ z0));
            c001.u = *(const unsigned*)(tlb + (a00 ^ z1));
            c010.u = *(const unsigned*)(tlb + (a01 ^ z0));
            c011.u = *(const unsigned*)(tlb + (a01 ^ z1));
            c100.u = *(const unsigned*)(tlb + (a10 ^ z0));
            c101.u = *(const unsigned*)(tlb + (a10 ^ z1));
            c110.u = *(const unsigned*)(tlb + (a11 ^ z0));
            c111.u = *(const unsigned*)(tlb + (a11 ^ z1));
            h2v zz00 = lerp2(c000.h, c001.h, wzp.h);
            h2v zz01 = lerp2(c010.h, c011.h, wzp.h);
            h2v zz10 = lerp2(c100.h, c101.h, wzp.h);
            h2v zz11 = lerp2(c110.h, c111.h, wzp.h);
            h2v yy0  = lerp2(zz00, zz01, wyp.h);
            h2v yy1  = lerp2(zz10, zz11, wyp.h);
            UH2 r; r.h = lerp2(yy0, yy1, wxp.h);
            hd[l] = r.u;                     // packed features (2l, 2l+1)
        }
        {   // encode->MLP transpose staging, stride 10 (4 b64 writes, 4-way max)
            unsigned* hp = hs + lane * 10;
            *(uint2*)&hp[0] = make_uint2(hd[0], hd[1]);
            *(uint2*)&hp[2] = make_uint2(hd[2], hd[3]);
            *(uint2*)&hp[4] = make_uint2(hd[4], hd[5]);
            *(uint2*)&hp[6] = make_uint2(hd[6], hd[7]);
        }

        // ---- MLP: 4 tiles of 16 points; everything after the B1 read is
        // register-resident (C-frag -> next B-frag via cvt_pkrtz only).
        #pragma unroll
        for (int t = 0; t < 4; ++t) {
            // B1: features q*4..q*4+3 of point t*16+m16 = dwords 2q,2q+1
            half4 b1 = as_h4(*(const uint2*)&hs[(t * 16 + m16) * 10 + 2 * q]);

            // L1: 16->64, relu
            half4 b2[4];
            #pragma unroll
            for (int mo = 0; mo < 4; ++mo) {
                floatx4 c = MFMA16(A1[mo], b1, cz);
                b2[mo] = as_h4(make_uint2(pkrelu(c[0], c[1]), pkrelu(c[2], c[3])));
            }
            // L2: 64->16, linear
            floatx4 c2 = cz;
            #pragma unroll
            for (int kc = 0; kc < 4; ++kc)
                c2 = MFMA16(A2[kc], b2[kc], c2);
            half4 b3 = as_h4(make_uint2(pk2(c2[0], c2[1]), pk2(c2[2], c2[3])));

            // L3: 16->64, relu
            half4 b4[4];
            #pragma unroll
            for (int mo = 0; mo < 4; ++mo) {
                floatx4 c = MFMA16(A3[mo], b3, cz);
                b4[mo] = as_h4(make_uint2(pkrelu(c[0], c[1]), pkrelu(c[2], c[3])));
            }
            // L4: 64->64 relu, fused with L5: z = relu(g) . r3
            float z = 0.f;
            #pragma unroll
            for (int mo = 0; mo < 4; ++mo) {
                floatx4 c = cz;
                #pragma unroll
                for (int kc = 0; kc < 4; ++kc)
                    c = MFMA16(A4[kc][mo], b4[kc], c);
                #pragma unroll
                for (int r = 0; r < 4; ++r)
                    z = fmaf(fmaxf(c[r], 0.f), r3v[mo * 4 + r], z);
            }
            z += __shfl_xor(z, 16);
            z += __shfl_xor(z, 32);
            if (lane < 16)
                out[pbase + wv * 64 + t * 16 + lane] = 1.0f / (1.0f + __expf(-z));
        }
    }
}

extern "C" void kernel_launch(void* const* d_in, const int* in_sizes, int n_in,
                              void* d_out, int out_size, void* d_ws, size_t ws_size,
                              hipStream_t stream)
{
    const float* x  = (const float*)d_in[0];
    const float* tb = (const float*)d_in[1];
    const float* w1 = (const float*)d_in[2];
    const float* w2 = (const float*)d_in[3];
    const float* r1 = (const float*)d_in[4];
    const float* r2 = (const float*)d_in[5];
    const float* r3 = (const float*)d_in[6];
    float* out = (float*)d_out;
    const int N = in_sizes[0] / 3;

    // Replicate numpy: B_SCALE = exp(log(20*0.5/2)/(L-1)); RES = floor(2*B^l)
    Res8 res;
    double b = exp(log(20.0 * 0.5 / 2.0) / (double)(NLVL - 1));
    for (int l = 0; l < NLVL; ++l)
        res.r[l] = (float)floor(2.0 * pow(b, (double)l));

    // 1024 blocks x 512 thr x 4 iters == 2M exactly. 52KB LDS/block -> up to
    // 3 blocks/CU if the allocator lands <=85 VGPRs (launch_bounds caps 128).
    const int blocks = 1024, threads = 512;
    const int iters = N / (blocks * threads);
    ngp_mfma_kernel<<<blocks, threads, 0, stream>>>(x, tb, w1, w2, r1, r2, r3,
                                                    out, N, iters, res);
}